// Round 1
// 612.418 us; speedup vs baseline: 1.0005x; 1.0005x over previous
//
#include <hip/hip_runtime.h>

#define BLK 128

typedef unsigned short u16;
typedef __attribute__((ext_vector_type(8)))  short bf16x8;
typedef __attribute__((ext_vector_type(8)))  unsigned short u16x8;
typedef __attribute__((ext_vector_type(4)))  unsigned short u16x4;
typedef __attribute__((ext_vector_type(4)))  float f32x4;
typedef __attribute__((ext_vector_type(16))) float f32x16;
typedef __attribute__((ext_vector_type(4)))  unsigned int u32x4;

struct KArgs { const void* p[29]; void* out; };

__device__ __forceinline__ float b2f(u16 u) { return __uint_as_float(((unsigned)u) << 16); }
__device__ __forceinline__ u16 f2b(float f) {
    unsigned x = __float_as_uint(f);
    return (u16)((x + 0x7FFFu + ((x >> 16) & 1u)) >> 16);   // RNE
}

// ---- epilogue chunk descriptors (verified R2): 31 chunks of 8 cols after hand_board
__device__ __constant__ unsigned char EP_KIND[31] = {
    0,0,0,0,0,0,0,0,0,0,0,0, 1,1,1,1, 0,0,0, 1, 0,0,0,0,0, 1,1,1,1,1,1 };
__device__ __constant__ unsigned char EP_P1[31] = {
    40,19,38,38,38,38,38,19,19,19,19,19, 0,2,3,5, 19,26,52, 1, 26,19,52,45,19, 4,4,4,4,4,4 };
__device__ __constant__ unsigned char EP_P2[31] = {
    18,20,22,23,24,25,26,27,28,29,30,31, 40,41,42,43, 35,36,37, 39, 32,33,34,19,38, 44,45,46,47,48,49 };

// ---- weight-arena layout (bf16, transposed wt[n][k], KP = K+8, N padded to mult-32)
// PL_PERM=1: the layer's input arrives in MFMA-D pack order (feature bits 2<->3 swapped
// relative to natural k order), so we pre-swap k bits 2<->3 in the arena. The two first
// layers (hand L1 / board L1) consume the natural-order card gather -> no permute.
__device__ __constant__ int PL_K[9]    = {64,80,64,80,64,80,144,144,64};
__device__ __constant__ int PL_N[9]    = {64,80,64,80,64,80,144,64,64};
__device__ __constant__ int PL_NC[9]   = {64,96,64,96,64,96,160,64,64};
__device__ __constant__ int PL_WOFF[9] = {0,4608,13056,17664,26112,30720,39168,63488,73216};
__device__ __constant__ int PL_BOFF[9] = {0,64,160,224,320,384,480,640,704};
__device__ __constant__ int PL_WIDX[9] = {3,9,5,11,7,13,15,17,19};
__device__ __constant__ int PL_PERM[9] = {0,0,1,1,1,1,1,1,1};
#define ARENA_ELEMS 77824
#define BIAS_BYTE_OFF 155648          // = ARENA_ELEMS*2, 16B aligned
#define FLAG_BYTE_OFF 158720          // after 768 bias floats

// dtype probe (verified R2): f32 layout -> these u16 positions are all zero
__global__ void dtype_probe(const u16* st, int* flag) {
    if (threadIdx.x == 0 && blockIdx.x == 0) {
        unsigned o = 0;
        #pragma unroll
        for (int j = 1; j <= 16; j++) o |= st[100 * j];
        *flag = (o == 0) ? 1 : 0;
    }
}

template<bool F32>
__global__ void poker_prep(KArgs a, u16* arena, float* biasar, const int* flag)
{
    if (*flag != (F32 ? 1 : 0)) return;
    const int L = blockIdx.x;
    const int K = PL_K[L], N = PL_N[L], NC = PL_NC[L], KP = K + 8;
    const int PM = PL_PERM[L];
    const void* W = a.p[PL_WIDX[L]];
    const void* b = a.p[PL_WIDX[L] + 1];
    u16* wt = arena + PL_WOFF[L];
    for (int e = threadIdx.x; e < NC * KP; e += blockDim.x) {
        int n = e / KP, k = e - n * KP;
        float v = 0.f;
        if (k < K && n < N) {
            int ks = PM ? ((k & ~12) | ((k & 4) << 1) | ((k & 8) >> 1)) : k;  // swap bits 2<->3
            v = F32 ? ((const float*)W)[ks * N + n] : b2f(((const u16*)W)[ks * N + n]);
        }
        wt[e] = f2b(v);
    }
    if ((int)threadIdx.x < NC) {
        float v = ((int)threadIdx.x < N)
            ? (F32 ? ((const float*)b)[threadIdx.x] : b2f(((const u16*)b)[threadIdx.x]))
            : 0.f;
        biasar[PL_BOFF[L] + threadIdx.x] = v;
    }
}

// One layer, activations fully in registers.
//   A = wt[n_out][kslot]  (arena k-permuted so kslot pairs with the D-pack feature order)
//   B = x fragments       (lane n = x-row = lane&31; chunk kappa, elem j -> kslot 16k+8h+j)
//   D: lane (r+32h) acc[t][4G+j] = out-feature 32t+8G+4h+j  -> pack into y[2t+s] directly:
//      y[c][e] = feature 16c + 8*(e>>2) + 4h + (e&3)   (the "D-pack" order)
template<int K, int NT, int NCO, bool ACT>
__device__ __forceinline__ void layerR(
    const u16* __restrict__ wt, const float* __restrict__ bias,
    const bf16x8* __restrict__ x, bf16x8* __restrict__ y, int lane)
{
    constexpr int KP = K + 8;
    const int h = lane >> 5, n32 = lane & 31;
    const u16* wp = wt + n32 * KP + h * 8;
    f32x16 acc[NT] = {};
    #pragma unroll
    for (int kk = 0; kk < K / 16; kk++) {
        #pragma unroll
        for (int t = 0; t < NT; t++) {
            bf16x8 wf = *(const bf16x8*)(wp + t * (32 * KP) + kk * 16);
            acc[t] = __builtin_amdgcn_mfma_f32_32x32x16_bf16(wf, x[kk], acc[t], 0, 0, 0);
        }
    }
    #pragma unroll
    for (int t = 0; t < NT; t++) {
        #pragma unroll
        for (int s = 0; s < 2; s++) {
            if (2 * t + s < NCO) {
                unsigned w[4];
                #pragma unroll
                for (int gg = 0; gg < 2; gg++) {
                    const int G = 2 * s + gg;
                    f32x4 bv = *(const f32x4*)(bias + t * 32 + 8 * G + 4 * h);
                    float v0 = acc[t][4 * G + 0] + bv[0];
                    float v1 = acc[t][4 * G + 1] + bv[1];
                    float v2 = acc[t][4 * G + 2] + bv[2];
                    float v3 = acc[t][4 * G + 3] + bv[3];
                    if (ACT) {
                        v0 = fmaxf(v0, 0.01f * v0); v1 = fmaxf(v1, 0.01f * v1);
                        v2 = fmaxf(v2, 0.01f * v2); v3 = fmaxf(v3, 0.01f * v3);
                    }
                    w[2 * gg + 0] = (unsigned)f2b(v0) | ((unsigned)f2b(v1) << 16);
                    w[2 * gg + 1] = (unsigned)f2b(v2) | ((unsigned)f2b(v3) << 16);
                }
                u32x4 fw = { w[0], w[1], w[2], w[3] };
                y[2 * t + s] = __builtin_bit_cast(bf16x8, fw);
            }
        }
    }
}

template<bool F32>
__global__ __launch_bounds__(BLK, 3) void poker_main(
    KArgs a, const u16* __restrict__ arena, const float* __restrict__ biasar, const int* flag)
{
    if (*flag != (F32 ? 1 : 0)) return;

    __shared__ alignas(16) u16   s_emb[54 * 8];   // suit0 rank5 pos19 act26 actv38 street40 nump45 blind52
    __shared__ alignas(16) float s_scalW[48];
    __shared__ alignas(16) float s_scalB[48];
    __shared__ alignas(16) u16   s_HB[2][32 * 72]; // per-wave hand_board transpose, stride 72 (bank-safe)

    const int tid = threadIdx.x;
    const int lane = tid & 63, wave = tid >> 6;
    const int rbase = wave * 32;
    const long row0 = (long)blockIdx.x * 64;

    // ---- block-wide staging of tiny tables (the only barrier in the kernel)
    {
        const void* srcs[8] = { a.p[1], a.p[2], a.p[21], a.p[22], a.p[23], a.p[24], a.p[25], a.p[26] };
        const int  cnt[8]   = { 5, 14, 7, 12, 2, 5, 7, 2 };
        int base = 0;
        for (int t = 0; t < 8; t++) {
            int n = cnt[t] * 8;
            for (int i = tid; i < n; i += BLK)
                s_emb[base + i] = F32 ? f2b(((const float*)srcs[t])[i]) : ((const u16*)srcs[t])[i];
            base += n;
        }
        if (tid < 48) {
            s_scalW[tid] = F32 ? ((const float*)a.p[27])[tid] : b2f(((const u16*)a.p[27])[tid]);
            s_scalB[tid] = F32 ? ((const float*)a.p[28])[tid] : b2f(((const u16*)a.p[28])[tid]);
        }
    }
    __syncthreads();

    const int h = lane >> 5, r = lane & 31;
    const long grow = row0 + rbase + r;

    // ---- card gather straight into register fragments (natural k order):
    // chunk c = card c; h=0 lane holds suit emb (feats 16c+0..7), h=1 lane rank emb (+8..15)
    bf16x8 xh[4], xb[5];
    #pragma unroll
    for (int c = 0; c < 9; c++) {
        int col = 2 * c + 1 - h;                    // suit col = 2c+1, rank col = 2c
        float fv;
        if constexpr (F32) fv = ((const float*)a.p[0])[grow * 50 + col];
        else               fv = b2f(((const u16*)a.p[0])[grow * 50 + col]);
        int idx = (int)(fv + 0.5f);
        bf16x8 ev = *(const bf16x8*)&s_emb[(h ? 5 + idx : idx) * 8];
        if (c < 4) xh[c] = ev; else xb[c - 4] = ev;
    }

    // ---- 9 layers, all activations in registers (weight arena k-permuted for layers 2+)
    bf16x8 h1[4], b1[5];
    layerR< 64, 2, 4, true >(arena + 0,     biasar + 0,   xh, h1, lane);     // hand L1
    layerR< 80, 3, 5, true >(arena + 4608,  biasar + 64,  xb, b1, lane);     // board L1
    bf16x8 h2[4], b2[5];
    layerR< 64, 2, 4, true >(arena + 13056, biasar + 160, h1, h2, lane);     // hand L2
    layerR< 80, 3, 5, true >(arena + 17664, biasar + 224, b1, b2, lane);     // board L2
    bf16x8 hb[9];
    layerR< 64, 2, 4, false>(arena + 26112, biasar + 320, h2, hb, lane);     // hand L3 -> hb[0..3]
    layerR< 80, 3, 5, false>(arena + 30720, biasar + 384, b2, hb + 4, lane); // board L3 -> hb[4..8]
    bf16x8 c1[9];   // hb L1 split (NT=3 + NT=2) to cap accumulator pressure
    layerR<144, 3, 6, true >(arena + 39168,         biasar + 480,      hb, c1, lane);
    layerR<144, 2, 3, true >(arena + 39168 + 14592, biasar + 480 + 96, hb, c1 + 6, lane);
    bf16x8 c2[4];
    layerR<144, 2, 4, true >(arena + 63488, biasar + 640, c1, c2, lane);     // hb L2
    bf16x8 c3[4];
    layerR< 64, 2, 4, false>(arena + 73216, biasar + 704, c2, c3, lane);     // hb L3

    // ---- de-swizzle final 64 feats into per-wave LDS (natural column order)
    // c3[c][e] = feature 16c + 8*(e>>2) + 4h + (e&3)
    u16* hbp = &s_HB[wave][0];
    #pragma unroll
    for (int c = 0; c < 4; c++) {
        u16x4 lo = { (u16)c3[c][0], (u16)c3[c][1], (u16)c3[c][2], (u16)c3[c][3] };
        u16x4 hi = { (u16)c3[c][4], (u16)c3[c][5], (u16)c3[c][6], (u16)c3[c][7] };
        *(u16x4*)&hbp[r * 72 + c * 16 + 4 * h]     = lo;
        *(u16x4*)&hbp[r * 72 + c * 16 + 8 + 4 * h] = hi;
    }
    // same-wave LDS write->read ordering is guaranteed by in-order DS + lgkmcnt (as before)

    // ---- per-wave epilogue: 312 cols = 39 chunks x 8, coalesced 32B (f32) stores.
    // Fully unrolled so the ~19 scattered state loads issue in parallel.
    #pragma unroll
    for (int i = 0; i < 20; i++) {
        int u = lane + 64 * i;
        if (u < 32 * 39) {
            int r2 = u / 39, c = u - 39 * r2;
            long g2 = row0 + rbase + r2;
            float v[8];
            if (c < 8) {
                u16x8 w = *(const u16x8*)&hbp[r2 * 72 + c * 8];   // hand_board
                #pragma unroll
                for (int j = 0; j < 8; j++) v[j] = b2f(w[j]);
            } else {
                int e = c - 8;
                int col = EP_P2[e], p1 = EP_P1[e];
                float sv;
                if constexpr (F32) sv = ((const float*)a.p[0])[g2 * 50 + col];
                else               sv = b2f(((const u16*)a.p[0])[g2 * 50 + col]);
                if (EP_KIND[e] == 0) {
                    int idx = (int)(sv + 0.5f);
                    u16x8 w = *(const u16x8*)&s_emb[(p1 + idx) * 8];
                    #pragma unroll
                    for (int j = 0; j < 8; j++) v[j] = b2f(w[j]);
                } else {
                    #pragma unroll
                    for (int j = 0; j < 8; j++) v[j] = fmaf(sv, s_scalW[p1 * 8 + j], s_scalB[p1 * 8 + j]);
                }
            }
            long base = g2 * 312 + c * 8;
            if constexpr (F32) {
                float* o = (float*)a.out;
                f32x4 lo = { v[0], v[1], v[2], v[3] };
                f32x4 hi = { v[4], v[5], v[6], v[7] };
                *(f32x4*)&o[base]     = lo;
                *(f32x4*)&o[base + 4] = hi;
            } else {
                u16x8 w;
                #pragma unroll
                for (int j = 0; j < 8; j++) w[j] = f2b(v[j]);
                *(u16x8*)&((u16*)a.out)[base] = w;
            }
        }
    }
}

extern "C" void kernel_launch(void* const* d_in, const int* in_sizes, int n_in,
                              void* d_out, int out_size, void* d_ws, size_t ws_size,
                              hipStream_t stream) {
    KArgs args;
    for (int i = 0; i < 29; i++) args.p[i] = d_in[i];
    args.out = d_out;
    u16*   arena  = (u16*)d_ws;
    float* biasar = (float*)((char*)d_ws + BIAS_BYTE_OFF);
    int*   flag   = (int*)((char*)d_ws + FLAG_BYTE_OFF);
    int rows = in_sizes[0] / 50;          // 262144
    int blocks = rows / 64;               // 4096

    dtype_probe<<<dim3(1), dim3(64), 0, stream>>>((const u16*)d_in[0], flag);
    poker_prep<false><<<dim3(9), dim3(256), 0, stream>>>(args, arena, biasar, flag);
    poker_prep<true ><<<dim3(9), dim3(256), 0, stream>>>(args, arena, biasar, flag);
    poker_main<false><<<dim3(blocks), dim3(BLK), 0, stream>>>(args, arena, biasar, flag);
    poker_main<true ><<<dim3(blocks), dim3(BLK), 0, stream>>>(args, arena, biasar, flag);
}

// Round 3
// 499.206 us; speedup vs baseline: 1.2274x; 1.2268x over previous
//
#include <hip/hip_runtime.h>

#define BLK 128

typedef unsigned short u16;
typedef __attribute__((ext_vector_type(8)))  short bf16x8;
typedef __attribute__((ext_vector_type(8)))  unsigned short u16x8;
typedef __attribute__((ext_vector_type(4)))  unsigned short u16x4;
typedef __attribute__((ext_vector_type(4)))  float f32x4;
typedef __attribute__((ext_vector_type(16))) float f32x16;
typedef __attribute__((ext_vector_type(4)))  unsigned int u32x4;

struct KArgs { const void* p[29]; void* out; };

__device__ __forceinline__ float b2f(u16 u) { return __uint_as_float(((unsigned)u) << 16); }
__device__ __forceinline__ u16 f2b(float f) {
    unsigned x = __float_as_uint(f);
    return (u16)((x + 0x7FFFu + ((x >> 16) & 1u)) >> 16);   // RNE
}

// ---- epilogue chunk descriptors (verified: 31 chunks of 8 cols after hand_board)
// chunk 20 = E(action_emb, LAST_AGRO_ACTION=32): EP_P1=26 (action table), EP_P2=32. (R2 bug: was 26)
__device__ __constant__ unsigned char EP_KIND[31] = {
    0,0,0,0,0,0,0,0,0,0,0,0, 1,1,1,1, 0,0,0, 1, 0,0,0,0,0, 1,1,1,1,1,1 };
__device__ __constant__ unsigned char EP_P1[31] = {
    40,19,38,38,38,38,38,19,19,19,19,19, 0,2,3,5, 19,26,52, 1, 26,19,52,45,19, 4,4,4,4,4,4 };
__device__ __constant__ unsigned char EP_P2[31] = {
    18,20,22,23,24,25,26,27,28,29,30,31, 40,41,42,43, 35,36,37, 39, 32,33,34,19,38, 44,45,46,47,48,49 };

// ---- fragment-ordered weight arena. 10 logical layers (hb L1 split in two).
// Fragment for lane l at (layer, kk, t) lives at WOFF + ((kk*NT + t)*64 + l)*8 u16.
// Value = W[ perm(k) * N + (NOFF + 32t + (l&31)) ], k = kk*16 + (l>>5)*8 + j.
// perm = swap k bits 2<->3 for layers consuming D-packed activations.
__device__ __constant__ int P2_K[10]    = {64,80,64,80,64,80,144,144,144,64};
__device__ __constant__ int P2_NT[10]   = {2,3,2,3,2,3,3,2,2,2};
__device__ __constant__ int P2_N[10]    = {64,80,64,80,64,80,144,144,64,64};
__device__ __constant__ int P2_NOFF[10] = {0,0,0,0,0,0,0,96,0,0};
__device__ __constant__ int P2_WOFF[10] = {0,4096,11776,15872,23552,27648,35328,49152,58368,67584};
__device__ __constant__ int P2_BOFF[10] = {0,64,160,224,320,384,480,576,640,704};
__device__ __constant__ int P2_WIDX[10] = {3,9,5,11,7,13,15,15,17,19};
__device__ __constant__ int P2_PERM[10] = {0,0,1,1,1,1,1,1,1,1};
#define BIAS_BYTE_OFF 155648          // arena = 71680 u16 = 143360 B < this; 16B aligned

__device__ __forceinline__ bool probe_f32(const void* st) {
    const u16* p = (const u16*)st;
    unsigned o = 0;
    #pragma unroll
    for (int j = 1; j <= 16; j++) o |= p[100 * j];
    return o == 0;                    // f32 layout: low16 of integral floats are 0
}

__global__ void poker_prep(KArgs a, u16* arena, float* biasar)
{
    const bool F32 = probe_f32(a.p[0]);
    const int L = blockIdx.x;
    const int K = P2_K[L], NT = P2_NT[L], N = P2_N[L], NO = P2_NOFF[L], PM = P2_PERM[L];
    const void* W = a.p[P2_WIDX[L]];
    const void* b = a.p[P2_WIDX[L] + 1];
    u16* wt = arena + P2_WOFF[L];
    const int total = NT * K * 32;    // u16 elems
    for (int e = threadIdx.x; e < total; e += blockDim.x) {
        int f = e >> 3, j = e & 7;
        int l = f & 63, fi = f >> 6;
        int kk = fi / NT, t = fi - kk * NT;
        int n = NO + 32 * t + (l & 31);
        int k = kk * 16 + ((l >> 5) << 3) + j;
        int ks = PM ? ((k & ~12) | ((k & 4) << 1) | ((k & 8) >> 1)) : k;  // swap bits 2<->3
        float v = 0.f;
        if (n < N)
            v = F32 ? ((const float*)W)[ks * N + n] : b2f(((const u16*)W)[ks * N + n]);
        wt[e] = f2b(v);
    }
    const int BN = NT * 32;
    if ((int)threadIdx.x < BN) {
        int n = NO + threadIdx.x;
        float v = (n < N)
            ? (F32 ? ((const float*)b)[n] : b2f(((const u16*)b)[n]))
            : 0.f;
        biasar[P2_BOFF[L] + threadIdx.x] = v;
    }
}

// One layer, activations in registers, weights as dense coalesced 1KB wave-loads,
// bias from LDS. D-pack output order (feature bits 2<->3 swapped; arena compensates).
template<int K, int NT, int NCO, bool ACT>
__device__ __forceinline__ void layerR(
    const u16* __restrict__ wt, const float* __restrict__ sb,
    const bf16x8* __restrict__ x, bf16x8* __restrict__ y, int lane)
{
    const int h = lane >> 5;
    const u16* wp = wt + lane * 8;
    f32x16 acc[NT] = {};
    #pragma unroll
    for (int kk = 0; kk < K / 16; kk++) {
        #pragma unroll
        for (int t = 0; t < NT; t++) {
            bf16x8 wf = *(const bf16x8*)(wp + (kk * NT + t) * 512);
            acc[t] = __builtin_amdgcn_mfma_f32_32x32x16_bf16(wf, x[kk], acc[t], 0, 0, 0);
        }
    }
    #pragma unroll
    for (int t = 0; t < NT; t++) {
        #pragma unroll
        for (int s = 0; s < 2; s++) {
            if (2 * t + s < NCO) {
                unsigned w[4];
                #pragma unroll
                for (int gg = 0; gg < 2; gg++) {
                    const int G = 2 * s + gg;
                    f32x4 bv = *(const f32x4*)(sb + t * 32 + 8 * G + 4 * h);
                    float v0 = acc[t][4 * G + 0] + bv[0];
                    float v1 = acc[t][4 * G + 1] + bv[1];
                    float v2 = acc[t][4 * G + 2] + bv[2];
                    float v3 = acc[t][4 * G + 3] + bv[3];
                    if (ACT) {
                        v0 = fmaxf(v0, 0.01f * v0); v1 = fmaxf(v1, 0.01f * v1);
                        v2 = fmaxf(v2, 0.01f * v2); v3 = fmaxf(v3, 0.01f * v3);
                    }
                    w[2 * gg + 0] = (unsigned)f2b(v0) | ((unsigned)f2b(v1) << 16);
                    w[2 * gg + 1] = (unsigned)f2b(v2) | ((unsigned)f2b(v3) << 16);
                }
                u32x4 fw = { w[0], w[1], w[2], w[3] };
                y[2 * t + s] = __builtin_bit_cast(bf16x8, fw);
            }
        }
    }
}

template<bool F32>
__device__ __forceinline__ void body(
    const KArgs& a, const u16* __restrict__ arena,
    u16* s_emb, float* s_scalW, float* s_scalB, float* sb,
    float* ss /*wave's 32x50 state*/, u16* hbp /*wave's 32x72 HB*/,
    int lane, int wave, long row0)
{
    const int rbase = wave * 32;
    const int h = lane >> 5, r = lane & 31;

    // ---- dense state staging: 32 rows x 200B = 6400B as one flat copy (16B aligned)
    if constexpr (F32) {
        const char* gb = (const char*)a.p[0] + (row0 + rbase) * 200;
        #pragma unroll
        for (int i = 0; i < 7; i++) {
            int fo = i * 1024 + lane * 16;
            if (fo < 6400)
                *(f32x4*)((char*)ss + fo) = *(const f32x4*)(gb + fo);
        }
    } else {
        const char* gb = (const char*)a.p[0] + (row0 + rbase) * 100;
        #pragma unroll
        for (int i = 0; i < 7; i++) {
            int uo = i * 512 + lane * 8;          // bytes into 3200B bf16 block
            if (uo < 3200) {
                u16x4 w = *(const u16x4*)(gb + uo);
                f32x4 v = { b2f(w[0]), b2f(w[1]), b2f(w[2]), b2f(w[3]) };
                *(f32x4*)((char*)ss + uo * 2) = v;
            }
        }
    }

    // ---- card gather from LDS state -> register fragments (natural k order)
    const float* srow = ss + r * 50;
    bf16x8 xh[4], xb[5];
    #pragma unroll
    for (int c = 0; c < 9; c++) {
        float fv = srow[2 * c + 1 - h];           // h=0: suit col, h=1: rank col
        int idx = (int)(fv + 0.5f);
        bf16x8 ev = *(const bf16x8*)&s_emb[(h ? 5 + idx : idx) * 8];
        if (c < 4) xh[c] = ev; else xb[c - 4] = ev;
    }

    // ---- 9 layers (hb L1 split), all activations in registers
    bf16x8 h1[4], b1[5];
    layerR< 64, 2, 4, true >(arena + 0,     sb + 0,   xh, h1, lane);
    layerR< 80, 3, 5, true >(arena + 4096,  sb + 64,  xb, b1, lane);
    bf16x8 h2[4], b2v[5];
    layerR< 64, 2, 4, true >(arena + 11776, sb + 160, h1, h2, lane);
    layerR< 80, 3, 5, true >(arena + 15872, sb + 224, b1, b2v, lane);
    bf16x8 hb[9];
    layerR< 64, 2, 4, false>(arena + 23552, sb + 320, h2, hb, lane);
    layerR< 80, 3, 5, false>(arena + 27648, sb + 384, b2v, hb + 4, lane);
    bf16x8 c1[9];
    layerR<144, 3, 6, true >(arena + 35328, sb + 480, hb, c1, lane);
    layerR<144, 2, 3, true >(arena + 49152, sb + 576, hb, c1 + 6, lane);
    bf16x8 c2[4];
    layerR<144, 2, 4, true >(arena + 58368, sb + 640, c1, c2, lane);
    bf16x8 c3[4];
    layerR< 64, 2, 4, false>(arena + 67584, sb + 704, c2, c3, lane);

    // ---- de-swizzle final 64 feats into per-wave LDS (natural column order)
    // c3[c][e] = feature 16c + 8*(e>>2) + 4h + (e&3)
    #pragma unroll
    for (int c = 0; c < 4; c++) {
        u16x4 lo = { (u16)c3[c][0], (u16)c3[c][1], (u16)c3[c][2], (u16)c3[c][3] };
        u16x4 hi = { (u16)c3[c][4], (u16)c3[c][5], (u16)c3[c][6], (u16)c3[c][7] };
        *(u16x4*)&hbp[r * 72 + c * 16 + 4 * h]     = lo;
        *(u16x4*)&hbp[r * 72 + c * 16 + 8 + 4 * h] = hi;
    }

    // ---- epilogue
    if constexpr (F32) {
        // paired: 2 lanes per 8-col chunk -> every store is a dense 1KB wave store
        float* obase = (float*)a.out + (row0 + rbase) * 312;
        const int hf = lane & 1, ql = lane >> 1;
        #pragma unroll 13
        for (int i = 0; i < 39; i++) {
            int q = 32 * i + ql;                  // q < 1248 always
            int r2 = q / 39, c = q - 39 * r2;
            f32x4 ov;
            if (c < 8) {
                u16x4 w = *(const u16x4*)&hbp[r2 * 72 + c * 8 + hf * 4];
                ov[0] = b2f(w[0]); ov[1] = b2f(w[1]); ov[2] = b2f(w[2]); ov[3] = b2f(w[3]);
            } else {
                int e = c - 8;
                int col = EP_P2[e], p1 = EP_P1[e];
                float sv = ss[r2 * 50 + col];
                if (EP_KIND[e] == 0) {
                    int idx = (int)(sv + 0.5f);
                    u16x4 w = *(const u16x4*)&s_emb[(p1 + idx) * 8 + hf * 4];
                    ov[0] = b2f(w[0]); ov[1] = b2f(w[1]); ov[2] = b2f(w[2]); ov[3] = b2f(w[3]);
                } else {
                    #pragma unroll
                    for (int j = 0; j < 4; j++)
                        ov[j] = fmaf(sv, s_scalW[p1 * 8 + hf * 4 + j], s_scalB[p1 * 8 + hf * 4 + j]);
                }
            }
            *(f32x4*)(obase + i * 256 + lane * 4) = ov;    // dense: lane*16B
        }
    } else {
        // bf16 out: 16B per chunk is already dense per-lane
        #pragma unroll
        for (int i = 0; i < 20; i++) {
            int u = lane + 64 * i;
            if (u < 1248) {
                int r2 = u / 39, c = u - 39 * r2;
                float v[8];
                if (c < 8) {
                    u16x8 w = *(const u16x8*)&hbp[r2 * 72 + c * 8];
                    #pragma unroll
                    for (int j = 0; j < 8; j++) v[j] = b2f(w[j]);
                } else {
                    int e = c - 8;
                    int col = EP_P2[e], p1 = EP_P1[e];
                    float sv = ss[r2 * 50 + col];
                    if (EP_KIND[e] == 0) {
                        int idx = (int)(sv + 0.5f);
                        u16x8 w = *(const u16x8*)&s_emb[(p1 + idx) * 8];
                        #pragma unroll
                        for (int j = 0; j < 8; j++) v[j] = b2f(w[j]);
                    } else {
                        #pragma unroll
                        for (int j = 0; j < 8; j++)
                            v[j] = fmaf(sv, s_scalW[p1 * 8 + j], s_scalB[p1 * 8 + j]);
                    }
                }
                u16x8 w;
                #pragma unroll
                for (int j = 0; j < 8; j++) w[j] = f2b(v[j]);
                *(u16x8*)&((u16*)a.out)[(row0 + rbase + r2) * 312 + c * 8] = w;
            }
        }
    }
}

__global__ __launch_bounds__(BLK, 3) void poker_main(
    KArgs a, const u16* __restrict__ arena, const float* __restrict__ biasar)
{
    __shared__ alignas(16) u16   s_emb[54 * 8];
    __shared__ alignas(16) float s_scalW[48];
    __shared__ alignas(16) float s_scalB[48];
    __shared__ alignas(16) float s_bias[768];
    __shared__ alignas(16) float s_state[2][32 * 50];
    __shared__ alignas(16) u16   s_HB[2][32 * 72];

    const int tid = threadIdx.x;
    const int lane = tid & 63, wave = tid >> 6;
    const long row0 = (long)blockIdx.x * 64;
    const bool isf32 = probe_f32(a.p[0]);

    // ---- block-wide staging of tiny tables (the only barrier in the kernel)
    {
        const void* srcs[8] = { a.p[1], a.p[2], a.p[21], a.p[22], a.p[23], a.p[24], a.p[25], a.p[26] };
        const int  cnt[8]   = { 5, 14, 7, 12, 2, 5, 7, 2 };
        int base = 0;
        for (int t = 0; t < 8; t++) {
            int n = cnt[t] * 8;
            for (int i = tid; i < n; i += BLK)
                s_emb[base + i] = isf32 ? f2b(((const float*)srcs[t])[i]) : ((const u16*)srcs[t])[i];
            base += n;
        }
        if (tid < 48) {
            s_scalW[tid] = isf32 ? ((const float*)a.p[27])[tid] : b2f(((const u16*)a.p[27])[tid]);
            s_scalB[tid] = isf32 ? ((const float*)a.p[28])[tid] : b2f(((const u16*)a.p[28])[tid]);
        }
        for (int i = tid; i < 192; i += BLK)
            ((f32x4*)s_bias)[i] = ((const f32x4*)biasar)[i];
    }
    __syncthreads();

    float* ss  = &s_state[wave][0];
    u16*   hbp = &s_HB[wave][0];
    if (isf32) body<true >(a, arena, s_emb, s_scalW, s_scalB, s_bias, ss, hbp, lane, wave, row0);
    else       body<false>(a, arena, s_emb, s_scalW, s_scalB, s_bias, ss, hbp, lane, wave, row0);
}

extern "C" void kernel_launch(void* const* d_in, const int* in_sizes, int n_in,
                              void* d_out, int out_size, void* d_ws, size_t ws_size,
                              hipStream_t stream) {
    KArgs args;
    for (int i = 0; i < 29; i++) args.p[i] = d_in[i];
    args.out = d_out;
    u16*   arena  = (u16*)d_ws;
    float* biasar = (float*)((char*)d_ws + BIAS_BYTE_OFF);
    int rows = in_sizes[0] / 50;          // 262144
    int blocks = rows / 64;               // 4096

    poker_prep<<<dim3(10), dim3(256), 0, stream>>>(args, arena, biasar);
    poker_main<<<dim3(blocks), dim3(BLK), 0, stream>>>(args, arena, biasar);
}

// Round 5
// 495.152 us; speedup vs baseline: 1.2375x; 1.0082x over previous
//
#include <hip/hip_runtime.h>

#define BLK 128
#define NFRAG 140      // total 1KB weight fragments in arena (consumed strictly in order)
#define PF 10          // rolling register-prefetch depth (fragments in flight)

typedef unsigned short u16;
typedef __attribute__((ext_vector_type(8)))  short bf16x8;
typedef __attribute__((ext_vector_type(8)))  unsigned short u16x8;
typedef __attribute__((ext_vector_type(4)))  unsigned short u16x4;
typedef __attribute__((ext_vector_type(4)))  float f32x4;
typedef __attribute__((ext_vector_type(16))) float f32x16;
typedef __attribute__((ext_vector_type(4)))  unsigned int u32x4;

struct KArgs { const void* p[29]; void* out; };

__device__ __forceinline__ float b2f(u16 u) { return __uint_as_float(((unsigned)u) << 16); }
__device__ __forceinline__ u16 f2b(float f) {
    unsigned x = __float_as_uint(f);
    return (u16)((x + 0x7FFFu + ((x >> 16) & 1u)) >> 16);   // RNE
}

// ---- epilogue chunk descriptors (verified; chunk20 = action_emb[col 32])
__device__ __constant__ unsigned char EP_KIND[31] = {
    0,0,0,0,0,0,0,0,0,0,0,0, 1,1,1,1, 0,0,0, 1, 0,0,0,0,0, 1,1,1,1,1,1 };
__device__ __constant__ unsigned char EP_P1[31] = {
    40,19,38,38,38,38,38,19,19,19,19,19, 0,2,3,5, 19,26,52, 1, 26,19,52,45,19, 4,4,4,4,4,4 };
__device__ __constant__ unsigned char EP_P2[31] = {
    18,20,22,23,24,25,26,27,28,29,30,31, 40,41,42,43, 35,36,37, 39, 32,33,34,19,38, 44,45,46,47,48,49 };

// ---- fragment-ordered weight arena (unchanged from R3). 10 logical layers.
// Fragment for lane l at (layer, kk, t) lives at WOFF + ((kk*NT + t)*64 + l)*8 u16.
// Value = W[ perm(k) * N + (NOFF + 32t + (l&31)) ], k = kk*16 + (l>>5)*8 + j.
__device__ __constant__ int P2_K[10]    = {64,80,64,80,64,80,144,144,144,64};
__device__ __constant__ int P2_NT[10]   = {2,3,2,3,2,3,3,2,2,2};
__device__ __constant__ int P2_N[10]    = {64,80,64,80,64,80,144,144,64,64};
__device__ __constant__ int P2_NOFF[10] = {0,0,0,0,0,0,0,96,0,0};
__device__ __constant__ int P2_WOFF[10] = {0,4096,11776,15872,23552,27648,35328,49152,58368,67584};
__device__ __constant__ int P2_BOFF[10] = {0,64,160,224,320,384,480,576,640,704};
__device__ __constant__ int P2_WIDX[10] = {3,9,5,11,7,13,15,15,17,19};
__device__ __constant__ int P2_PERM[10] = {0,0,1,1,1,1,1,1,1,1};
#define BIAS_BYTE_OFF 155648          // arena = 71680 u16 = 143360 B < this; 16B aligned

__device__ __forceinline__ bool probe_f32(const void* st) {
    const u16* p = (const u16*)st;
    unsigned o = 0;
    #pragma unroll
    for (int j = 1; j <= 16; j++) o |= p[100 * j];
    return o == 0;                    // f32 layout: low16 of integral floats are 0
}

__global__ void poker_prep(KArgs a, u16* arena, float* biasar)
{
    const bool F32 = probe_f32(a.p[0]);
    const int L = blockIdx.x;
    const int K = P2_K[L], NT = P2_NT[L], N = P2_N[L], NO = P2_NOFF[L], PM = P2_PERM[L];
    const void* W = a.p[P2_WIDX[L]];
    const void* b = a.p[P2_WIDX[L] + 1];
    u16* wt = arena + P2_WOFF[L];
    const int total = NT * K * 32;    // u16 elems
    for (int e = threadIdx.x; e < total; e += blockDim.x) {
        int f = e >> 3, j = e & 7;
        int l = f & 63, fi = f >> 6;
        int kk = fi / NT, t = fi - kk * NT;
        int n = NO + 32 * t + (l & 31);
        int k = kk * 16 + ((l >> 5) << 3) + j;
        int ks = PM ? ((k & ~12) | ((k & 4) << 1) | ((k & 8) >> 1)) : k;  // swap bits 2<->3
        float v = 0.f;
        if (n < N)
            v = F32 ? ((const float*)W)[ks * N + n] : b2f(((const u16*)W)[ks * N + n]);
        wt[e] = f2b(v);
    }
    const int BN = NT * 32;
    if ((int)threadIdx.x < BN) {
        int n = NO + threadIdx.x;
        float v = (n < N)
            ? (F32 ? ((const float*)b)[n] : b2f(((const u16*)b)[n]))
            : 0.f;
        biasar[P2_BOFF[L] + threadIdx.x] = v;
    }
}

// One layer. Weights flow through a PF-deep rolling register buffer shared across
// layers: invariant at entry = frags F0..F0+PF-1 are resident/in-flight in
// wbuf[(F0+i)%PF]. Each iteration consumes wbuf[f%PF] and re-loads it with frag
// f+PF. All indices compile-time constant after unroll -> pure registers; the
// compiler inserts its own counted vmcnt waits (no manual waitcnt, no races).
template<int F0, int K, int NT, int NCO, bool ACT>
__device__ __forceinline__ void layerQ(
    const u16* __restrict__ arena, bf16x8 (&wbuf)[PF],
    const float* __restrict__ sb,
    const bf16x8* __restrict__ x, bf16x8* __restrict__ y, int lane)
{
    const int h = lane >> 5;
    f32x16 acc[NT] = {};
    #pragma unroll
    for (int kk = 0; kk < K / 16; kk++) {
        #pragma unroll
        for (int t = 0; t < NT; t++) {
            const int f = F0 + kk * NT + t;      // constant after unroll
            bf16x8 w = wbuf[f % PF];
            if (f + PF < NFRAG)
                wbuf[f % PF] = *(const bf16x8*)(arena + (f + PF) * 512 + lane * 8);
            acc[t] = __builtin_amdgcn_mfma_f32_32x32x16_bf16(w, x[kk], acc[t], 0, 0, 0);
        }
    }
    #pragma unroll
    for (int t = 0; t < NT; t++) {
        #pragma unroll
        for (int s = 0; s < 2; s++) {
            if (2 * t + s < NCO) {
                unsigned w[4];
                #pragma unroll
                for (int gg = 0; gg < 2; gg++) {
                    const int G = 2 * s + gg;
                    f32x4 bv = *(const f32x4*)(sb + t * 32 + 8 * G + 4 * h);
                    float v0 = acc[t][4 * G + 0] + bv[0];
                    float v1 = acc[t][4 * G + 1] + bv[1];
                    float v2 = acc[t][4 * G + 2] + bv[2];
                    float v3 = acc[t][4 * G + 3] + bv[3];
                    if (ACT) {
                        v0 = fmaxf(v0, 0.01f * v0); v1 = fmaxf(v1, 0.01f * v1);
                        v2 = fmaxf(v2, 0.01f * v2); v3 = fmaxf(v3, 0.01f * v3);
                    }
                    w[2 * gg + 0] = (unsigned)f2b(v0) | ((unsigned)f2b(v1) << 16);
                    w[2 * gg + 1] = (unsigned)f2b(v2) | ((unsigned)f2b(v3) << 16);
                }
                u32x4 fw = { w[0], w[1], w[2], w[3] };
                y[2 * t + s] = __builtin_bit_cast(bf16x8, fw);
            }
        }
    }
}

template<bool F32>
__device__ __forceinline__ void body(
    const KArgs& a, const u16* __restrict__ arena,
    u16* s_emb, float* s_scalW, float* s_scalB, float* sb,
    float* ss /*wave's 32x50 state*/, u16* hbp /*wave's 32x72 HB*/,
    int lane, int wave, long row0)
{
    const int rbase = wave * 32;
    const int h = lane >> 5, r = lane & 31;

    // ---- dense state staging: 32 rows x 200B (f32) / 100B (bf16) flat copy into LDS f32
    if constexpr (F32) {
        const char* gb = (const char*)a.p[0] + (row0 + rbase) * 200;
        #pragma unroll
        for (int i = 0; i < 7; i++) {
            int fo = i * 1024 + lane * 16;
            if (fo < 6400)
                *(f32x4*)((char*)ss + fo) = *(const f32x4*)(gb + fo);
        }
    } else {
        const char* gb = (const char*)a.p[0] + (row0 + rbase) * 100;
        #pragma unroll
        for (int i = 0; i < 7; i++) {
            int uo = i * 512 + lane * 8;
            if (uo < 3200) {
                u16x4 w = *(const u16x4*)(gb + uo);
                f32x4 v = { b2f(w[0]), b2f(w[1]), b2f(w[2]), b2f(w[3]) };
                *(f32x4*)((char*)ss + uo * 2) = v;
            }
        }
    }

    // ---- card gather from LDS state -> register fragments (natural k order)
    const float* srow = ss + r * 50;
    bf16x8 xh[4], xb[5];
    #pragma unroll
    for (int c = 0; c < 9; c++) {
        float fv = srow[2 * c + 1 - h];           // h=0: suit col, h=1: rank col
        int idx = (int)(fv + 0.5f);
        bf16x8 ev = *(const bf16x8*)&s_emb[(h ? 5 + idx : idx) * 8];
        if (c < 4) xh[c] = ev; else xb[c - 4] = ev;
    }

    // ---- weight-pipeline prologue: load first PF fragments (frag p -> wbuf[p])
    bf16x8 wbuf[PF];
    #pragma unroll
    for (int p = 0; p < PF; p++)
        wbuf[p] = *(const bf16x8*)(arena + p * 512 + lane * 8);

    // ---- 10 pipelined layers (frag stream: 0,8,23,31,46,54,69,96,114,132; end 140)
    bf16x8 h1[4], b1[5];
    layerQ<  0,  64, 2, 4, true >(arena, wbuf, sb + 0,   xh, h1, lane);
    layerQ<  8,  80, 3, 5, true >(arena, wbuf, sb + 64,  xb, b1, lane);
    bf16x8 h2[4], b2v[5];
    layerQ< 23,  64, 2, 4, true >(arena, wbuf, sb + 160, h1, h2, lane);
    layerQ< 31,  80, 3, 5, true >(arena, wbuf, sb + 224, b1, b2v, lane);
    bf16x8 hb[9];
    layerQ< 46,  64, 2, 4, false>(arena, wbuf, sb + 320, h2, hb, lane);
    layerQ< 54,  80, 3, 5, false>(arena, wbuf, sb + 384, b2v, hb + 4, lane);
    bf16x8 c1[9];
    layerQ< 69, 144, 3, 6, true >(arena, wbuf, sb + 480, hb, c1, lane);
    layerQ< 96, 144, 2, 3, true >(arena, wbuf, sb + 576, hb, c1 + 6, lane);
    bf16x8 c2[4];
    layerQ<114, 144, 2, 4, true >(arena, wbuf, sb + 640, c1, c2, lane);
    bf16x8 c3[4];
    layerQ<132,  64, 2, 4, false>(arena, wbuf, sb + 704, c2, c3, lane);

    // ---- de-swizzle final 64 feats into per-wave LDS (natural column order)
    // c3[c][e] = feature 16c + 8*(e>>2) + 4h + (e&3)
    #pragma unroll
    for (int c = 0; c < 4; c++) {
        u16x4 lo = { (u16)c3[c][0], (u16)c3[c][1], (u16)c3[c][2], (u16)c3[c][3] };
        u16x4 hi = { (u16)c3[c][4], (u16)c3[c][5], (u16)c3[c][6], (u16)c3[c][7] };
        *(u16x4*)&hbp[r * 72 + c * 16 + 4 * h]     = lo;
        *(u16x4*)&hbp[r * 72 + c * 16 + 8 + 4 * h] = hi;
    }

    // ---- epilogue
    if constexpr (F32) {
        float* obase = (float*)a.out + (row0 + rbase) * 312;
        const int hf = lane & 1, ql = lane >> 1;
        #pragma unroll 13
        for (int i = 0; i < 39; i++) {
            int q = 32 * i + ql;
            int r2 = q / 39, c = q - 39 * r2;
            f32x4 ov;
            if (c < 8) {
                u16x4 w = *(const u16x4*)&hbp[r2 * 72 + c * 8 + hf * 4];
                ov[0] = b2f(w[0]); ov[1] = b2f(w[1]); ov[2] = b2f(w[2]); ov[3] = b2f(w[3]);
            } else {
                int e = c - 8;
                int col = EP_P2[e], p1 = EP_P1[e];
                float sv = ss[r2 * 50 + col];
                if (EP_KIND[e] == 0) {
                    int idx = (int)(sv + 0.5f);
                    u16x4 w = *(const u16x4*)&s_emb[(p1 + idx) * 8 + hf * 4];
                    ov[0] = b2f(w[0]); ov[1] = b2f(w[1]); ov[2] = b2f(w[2]); ov[3] = b2f(w[3]);
                } else {
                    #pragma unroll
                    for (int j = 0; j < 4; j++)
                        ov[j] = fmaf(sv, s_scalW[p1 * 8 + hf * 4 + j], s_scalB[p1 * 8 + hf * 4 + j]);
                }
            }
            *(f32x4*)(obase + i * 256 + lane * 4) = ov;
        }
    } else {
        #pragma unroll
        for (int i = 0; i < 20; i++) {
            int u = lane + 64 * i;
            if (u < 1248) {
                int r2 = u / 39, c = u - 39 * r2;
                float v[8];
                if (c < 8) {
                    u16x8 w = *(const u16x8*)&hbp[r2 * 72 + c * 8];
                    #pragma unroll
                    for (int j = 0; j < 8; j++) v[j] = b2f(w[j]);
                } else {
                    int e = c - 8;
                    int col = EP_P2[e], p1 = EP_P1[e];
                    float sv = ss[r2 * 50 + col];
                    if (EP_KIND[e] == 0) {
                        int idx = (int)(sv + 0.5f);
                        u16x8 w = *(const u16x8*)&s_emb[(p1 + idx) * 8];
                        #pragma unroll
                        for (int j = 0; j < 8; j++) v[j] = b2f(w[j]);
                    } else {
                        #pragma unroll
                        for (int j = 0; j < 8; j++)
                            v[j] = fmaf(sv, s_scalW[p1 * 8 + j], s_scalB[p1 * 8 + j]);
                    }
                }
                u16x8 w;
                #pragma unroll
                for (int j = 0; j < 8; j++) w[j] = f2b(v[j]);
                *(u16x8*)&((u16*)a.out)[(row0 + rbase + r2) * 312 + c * 8] = w;
            }
        }
    }
}

__global__ __launch_bounds__(BLK, 2) void poker_main(
    KArgs a, const u16* __restrict__ arena, const float* __restrict__ biasar)
{
    __shared__ alignas(16) u16   s_emb[54 * 8];
    __shared__ alignas(16) float s_scalW[48];
    __shared__ alignas(16) float s_scalB[48];
    __shared__ alignas(16) float s_bias[768];
    __shared__ alignas(16) float s_state[2][32 * 50];
    __shared__ alignas(16) u16   s_HB[2][32 * 72];

    const int tid = threadIdx.x;
    const int lane = tid & 63, wave = tid >> 6;
    const long row0 = (long)blockIdx.x * 64;
    const bool isf32 = probe_f32(a.p[0]);

    // ---- block-wide staging of tiny tables (the only barrier in the kernel)
    {
        const void* srcs[8] = { a.p[1], a.p[2], a.p[21], a.p[22], a.p[23], a.p[24], a.p[25], a.p[26] };
        const int  cnt[8]   = { 5, 14, 7, 12, 2, 5, 7, 2 };
        int base = 0;
        for (int t = 0; t < 8; t++) {
            int n = cnt[t] * 8;
            for (int i = tid; i < n; i += BLK)
                s_emb[base + i] = isf32 ? f2b(((const float*)srcs[t])[i]) : ((const u16*)srcs[t])[i];
            base += n;
        }
        if (tid < 48) {
            s_scalW[tid] = isf32 ? ((const float*)a.p[27])[tid] : b2f(((const u16*)a.p[27])[tid]);
            s_scalB[tid] = isf32 ? ((const float*)a.p[28])[tid] : b2f(((const u16*)a.p[28])[tid]);
        }
        for (int i = tid; i < 192; i += BLK)
            ((f32x4*)s_bias)[i] = ((const f32x4*)biasar)[i];
    }
    __syncthreads();

    float* ss  = &s_state[wave][0];
    u16*   hbp = &s_HB[wave][0];
    if (isf32) body<true >(a, arena, s_emb, s_scalW, s_scalB, s_bias, ss, hbp, lane, wave, row0);
    else       body<false>(a, arena, s_emb, s_scalW, s_scalB, s_bias, ss, hbp, lane, wave, row0);
}

extern "C" void kernel_launch(void* const* d_in, const int* in_sizes, int n_in,
                              void* d_out, int out_size, void* d_ws, size_t ws_size,
                              hipStream_t stream) {
    KArgs args;
    for (int i = 0; i < 29; i++) args.p[i] = d_in[i];
    args.out = d_out;
    u16*   arena  = (u16*)d_ws;
    float* biasar = (float*)((char*)d_ws + BIAS_BYTE_OFF);
    int rows = in_sizes[0] / 50;          // 262144
    int blocks = rows / 64;               // 4096

    poker_prep<<<dim3(10), dim3(256), 0, stream>>>(args, arena, biasar);
    poker_main<<<dim3(blocks), dim3(BLK), 0, stream>>>(args, arena, biasar);
}